// Round 13
// baseline (572.688 us; speedup 1.0000x reference)
//
#include <hip/hip_runtime.h>
#include <float.h>

#define DECAY 0.99f
#define EPS 1e-5f
#define NROWS 65536
#define DIM 256
#define NEMB 1024
#define CH 64            // rows per sub-chunk in segmented reduction
#define MAXSUB 2048      // NROWS/CH + NEMB upper bound on total sub-chunks
#define WND 0.5f         // candidate window (f16 dist err: rms 0.022, max@67M ~0.15)

#define GLOBAL_AS __attribute__((address_space(1)))
#define LOCAL_AS  __attribute__((address_space(3)))

typedef _Float16 f16;
typedef _Float16 half8 __attribute__((ext_vector_type(8)));
typedef float f32x4 __attribute__((ext_vector_type(4)));

// ---------- K0a: ||e_k||^2 per code + zero counts + zero nflag ----------
__global__ __launch_bounds__(256) void k_enorm(const float* __restrict__ embed,
                                               float* __restrict__ enorm2,
                                               int* __restrict__ counts,
                                               int* __restrict__ nflag) {
    int kk = threadIdx.x & 63;
    int dg = threadIdx.x >> 6;              // 0..3
    int k  = blockIdx.x * 64 + kk;          // 16 blocks * 64 = 1024 codes
    float s = 0.f;
    for (int d = dg; d < DIM; d += 4) {
        float v = embed[(size_t)d * NEMB + k];
        s = fmaf(v, v, s);
    }
    __shared__ float red[4][64];
    red[dg][kk] = s;
    __syncthreads();
    if (dg == 0) enorm2[k] = red[0][kk] + red[1][kk] + red[2][kk] + red[3][kk];
    int gt = blockIdx.x * 256 + threadIdx.x;
    if (gt < NEMB) counts[gt] = 0;
    if (blockIdx.x == 0 && threadIdx.x == 0) nflag[0] = 0;
}

// ---------- K0b: fused transpose (embedT fp32) + f16-hi split (ehT [1024][256]) ----------
__global__ __launch_bounds__(256) void k_prep(const float* __restrict__ embed,
                                              float* __restrict__ embedT,
                                              f16* __restrict__ ehT) {
    __shared__ float tile[32][33];           // [d-local][c-local]
    int c0 = blockIdx.x * 32, d0 = blockIdx.y * 32;
    int tx = threadIdx.x, ty = threadIdx.y;  // 32 x 8
#pragma unroll
    for (int i = 0; i < 4; i++)
        tile[ty + 8 * i][tx] = embed[(size_t)(d0 + ty + 8 * i) * NEMB + c0 + tx];
    __syncthreads();
#pragma unroll
    for (int i = 0; i < 4; i++) {
        int c = c0 + ty + 8 * i;
        int d = d0 + tx;
        float v = tile[tx][ty + 8 * i];
        embedT[(size_t)c * DIM + d] = v;
        ehT[(size_t)c * 256 + d] = (f16)v;
    }
}

// ---------- K1: stage-1 GEMM-argmin: A+B both LDS-resident, ONE barrier, no restaging ----------
// Block = 64 rows x 256 cols. Grid = 1024 rowblocks x 4 colblocks = 4096 (bx>>2 = rowblock).
// A: [64 rows][256 k] f16 = 32KB, byte = row*512 + ((slot*16)^((row&7)<<4)).
// B: [256 cols][256 k] f16 = 128KB, byte = col*512 + ((slot*16)^((col&7)<<4)),
//    staged by global_load_lds: thread t, iter it -> col = it*8+(t>>5), phys slot t&31,
//    logical slot = (t&31)^(t>>5)  [since col&7 == t>>5].
// 4 waves, wave w = cols w*64..+64 (all 64 rows). 8 K-steps, zero inner barriers.
// Output: per (row, 64-col chunk): (v1, i1, v2) -> tbl[row][16] (in out_q region).
#define LDS_A  0        // 32KB
#define LDS_B  32768    // 128KB
#define LDS_SZ 163840

__global__ __launch_bounds__(256, 1) void k_argmin_mfma(const float* __restrict__ input,
                                                        const f16* __restrict__ ehT,
                                                        const float* __restrict__ enorm2,
                                                        float4* __restrict__ tbl) {
    __shared__ char lds[LDS_SZ];
    const int tid  = threadIdx.x;
    const int lane = tid & 63;
    const int w    = tid >> 6;        // wave 0..3: cols w*64 within the 256-col slab
    const int bx   = blockIdx.x;
    const int rb   = (bx >> 2) * 64;
    const int cbi  = bx & 3;
    const int cb   = cbi * 256;
    const int l15  = lane & 15;
    const int lkh  = lane >> 4;       // 0..3

    // ---- issue B staging: 32 x global_load_lds per thread (128KB total) ----
    const int srow = tid >> 5;               // == col&7 for this thread's chunks
    const int slog = (tid & 31) ^ srow;      // logical k-slot to fetch
#pragma unroll
    for (int it = 0; it < 32; ++it) {
        const f16* src = ehT + (size_t)(cb + it * 8 + srow) * 256 + slog * 8;
        __builtin_amdgcn_global_load_lds((const GLOBAL_AS unsigned*)src,
            (LOCAL_AS unsigned*)(lds + LDS_B + it * 4096 + tid * 16), 16, 0, 0);
    }

    // e2 per output col fragment
    float e2a[4];
#pragma unroll
    for (int fc = 0; fc < 4; fc++) e2a[fc] = enorm2[cb + w * 64 + fc * 16 + l15];

    // ---- stage A: 64 rows x 256 d fp32 -> f16, swizzled ----
#pragma unroll
    for (int it4 = 0; it4 < 4; it4++) {
        int task = tid + 256 * it4;          // 0..1023
        int row = task >> 4, ch = task & 15; // ch = 16-d chunk
        const float4* g = (const float4*)(input + (size_t)(rb + row) * DIM + ch * 16);
        float fv[16];
        *(float4*)(fv + 0)  = g[0];
        *(float4*)(fv + 4)  = g[1];
        *(float4*)(fv + 8)  = g[2];
        *(float4*)(fv + 12) = g[3];
        half8 hh[2];
#pragma unroll
        for (int u = 0; u < 2; u++)
#pragma unroll
            for (int e = 0; e < 8; e++) hh[u][e] = (f16)fv[u * 8 + e];
        int rbase = row * 512;
        int sw = (row & 7) << 4;
        *(half8*)(lds + LDS_A + rbase + (((ch * 2    ) * 16) ^ sw)) = hh[0];
        *(half8*)(lds + LDS_A + rbase + (((ch * 2 + 1) * 16) ^ sw)) = hh[1];
    }
    __syncthreads();   // the ONLY barrier: A + B fully resident, never rewritten

    // ---- 8 K-steps, no barriers ----
    f32x4 acc[4][4];
#pragma unroll
    for (int fr = 0; fr < 4; fr++)
#pragma unroll
        for (int fc = 0; fc < 4; fc++) acc[fr][fc] = (f32x4){0.f, 0.f, 0.f, 0.f};

#pragma unroll
    for (int kt = 0; kt < 8; kt++) {
        const int slot = kt * 4 + lkh;
        half8 af[4], bf[4];
#pragma unroll
        for (int f = 0; f < 4; f++) {
            int row = f * 16 + l15;
            af[f] = *(const half8*)(lds + LDS_A + row * 512 + ((slot * 16) ^ ((row & 7) << 4)));
        }
#pragma unroll
        for (int f = 0; f < 4; f++) {
            int col = w * 64 + f * 16 + l15;
            bf[f] = *(const half8*)(lds + LDS_B + col * 512 + ((slot * 16) ^ ((col & 7) << 4)));
        }
        __builtin_amdgcn_s_setprio(1);
#pragma unroll
        for (int fr = 0; fr < 4; fr++)
#pragma unroll
            for (int fc = 0; fc < 4; fc++)
                acc[fr][fc] = __builtin_amdgcn_mfma_f32_16x16x32_f16(
                    af[fr], bf[fc], acc[fr][fc], 0, 0, 0);
        __builtin_amdgcn_s_setprio(0);
    }

    // ---- epilogue: per-row (v1,i1,v2) over this wave's 64 cols ----
    float v1[16], v2[16];
    int   i1[16];
#pragma unroll
    for (int fr = 0; fr < 4; fr++)
#pragma unroll
        for (int r = 0; r < 4; r++) {
            const int q = fr * 4 + r;
            float s = fmaf(-2.f, acc[fr][0][r], e2a[0]);
            v1[q] = s; i1[q] = cb + w * 64 + l15; v2[q] = FLT_MAX;
#pragma unroll
            for (int fc = 1; fc < 4; fc++) {
                float s2 = fmaf(-2.f, acc[fr][fc][r], e2a[fc]);
                int col = cb + w * 64 + fc * 16 + l15;
                if (s2 < v1[q]) { v2[q] = v1[q]; v1[q] = s2; i1[q] = col; }
                else if (s2 < v2[q]) v2[q] = s2;
            }
        }
    // merge across the 16 col-lanes (xor <= 8 stays within l15 group)
#pragma unroll
    for (int m = 1; m <= 8; m <<= 1) {
#pragma unroll
        for (int q = 0; q < 16; q++) {
            float ov1 = __shfl_xor(v1[q], m, 64);
            int   oi1 = __shfl_xor(i1[q], m, 64);
            float ov2 = __shfl_xor(v2[q], m, 64);
            if (ov1 < v1[q] || (ov1 == v1[q] && oi1 < i1[q])) {
                v2[q] = fminf(v1[q], ov2);
                v1[q] = ov1; i1[q] = oi1;
            } else {
                v2[q] = fminf(v2[q], ov1);
            }
        }
    }
    if (l15 == 0) {
        const int chunk = cbi * 4 + w;
#pragma unroll
        for (int fr = 0; fr < 4; fr++)
#pragma unroll
            for (int r = 0; r < 4; r++) {
                const int q = fr * 4 + r;
                const int row = rb + fr * 16 + lkh * 4 + r;
                float4 o;
                o.x = v1[q]; o.y = __int_as_float(i1[q]); o.z = v2[q]; o.w = 0.f;
                tbl[(size_t)row * 16 + chunk] = o;
            }
    }
}

// ---------- K1b: stage-2 resolve: merge 16 chunks, exact-check candidates ----------
__global__ __launch_bounds__(256) void k_resolve(const float* __restrict__ input,
                                                 const float* __restrict__ embedT,
                                                 const float* __restrict__ enorm2,
                                                 const float4* __restrict__ tbl,
                                                 int* __restrict__ ind,
                                                 float* __restrict__ out_ind,
                                                 int* __restrict__ counts,
                                                 unsigned char* __restrict__ flags) {
    const int lane = threadIdx.x & 63;
    const int w    = threadIdx.x >> 6;
    const int row  = blockIdx.x * 4 + w;     // wave-per-row
    const int c    = lane & 15;
    float4 t = tbl[(size_t)row * 16 + c];
    float v1 = t.x; int i1 = __float_as_int(t.y); float v2 = t.z;
    // global f16 min over 16 chunks
    float gv = v1; int gi = i1;
#pragma unroll
    for (int m = 1; m <= 8; m <<= 1) {
        float ov = __shfl_xor(gv, m, 64);
        int   oi = __shfl_xor(gi, m, 64);
        if (ov < gv || (ov == gv && oi < gi)) { gv = ov; gi = oi; }
    }
    const float wnd = gv + WND;
    // hard: some chunk's unindexed 2nd-best is inside the window
    if (__any(v2 <= wnd)) {
        if (lane == 0) flags[row] = 1;
        return;
    }
    unsigned long long cm = __ballot(v1 <= wnd);
    int nc = __popcll(cm & 0xFFFFull);
    int winner = gi;
    if (nc > 1) {
        // exact fp32 distance for each candidate (64-lane dot)
        const float4 xv = *(const float4*)(input + (size_t)row * DIM + lane * 4);
        float bd = FLT_MAX; int bi_ = 0x7fffffff;
        for (int cc = 0; cc < 16; ++cc) {
            float cv = __shfl(v1, cc, 64);
            int   ci = __shfl(i1, cc, 64);
            if (cv <= wnd) {
                const float4 ev = *(const float4*)(embedT + (size_t)ci * DIM + lane * 4);
                float p = xv.x * ev.x;
                p = fmaf(xv.y, ev.y, p);
                p = fmaf(xv.z, ev.z, p);
                p = fmaf(xv.w, ev.w, p);
#pragma unroll
                for (int mm = 1; mm <= 32; mm <<= 1) p += __shfl_xor(p, mm, 64);
                float dist = fmaf(-2.f, p, enorm2[ci]);
                if (dist < bd || (dist == bd && ci < bi_)) { bd = dist; bi_ = ci; }
            }
        }
        winner = bi_;
    }
    if (lane == 0) {
        ind[row] = winner;
        out_ind[row] = (float)winner;
        atomicAdd(&counts[winner], 1);
        flags[row] = 0;
    }
}

// ---------- K1c: compact flagged rows (order-free; per-row results independent) ----------
__global__ __launch_bounds__(256) void k_compact(const unsigned char* __restrict__ flags,
                                                 int* __restrict__ nflag,
                                                 int* __restrict__ flaglist) {
    int i = blockIdx.x * 256 + threadIdx.x;
    if (flags[i]) { int p = atomicAdd(nflag, 1); flaglist[p] = i; }
}

// ---------- K1d: exact fp32 full scan for hard rows (R12 engine) ----------
__global__ __launch_bounds__(256) void k_fix(const float* __restrict__ input,
                                             const float* __restrict__ embed,
                                             const float* __restrict__ enorm2,
                                             const int* __restrict__ flaglist,
                                             const int* __restrict__ nflag,
                                             int* __restrict__ ind,
                                             float* __restrict__ out_ind,
                                             int* __restrict__ counts) {
    const int total = nflag[0];
    const int base  = blockIdx.x * 8;
    if (base >= total) return;
    const int nr = min(8, total - base);
    __shared__ float xs[8][256];
    __shared__ float rv[8][256];
    __shared__ int   ri[8][256];
    const int t = threadIdx.x;
    for (int j = 0; j < nr; j++) {
        int row = flaglist[base + j];
        xs[j][t] = input[(size_t)row * DIM + t];
    }
    for (int j = nr; j < 8; j++) xs[j][t] = 0.f;
    __syncthreads();

    float best[8]; int bidx[8];
#pragma unroll
    for (int j = 0; j < 8; j++) { best[j] = FLT_MAX; bidx[j] = 0x7fffffff; }

    for (int cc = 0; cc < 4; cc++) {
        const int c = cc * 256 + t;
        float s[8];
#pragma unroll
        for (int j = 0; j < 8; j++) s[j] = 0.f;
        for (int d0 = 0; d0 < 256; d0 += 8) {
            float ev[8];
#pragma unroll
            for (int u = 0; u < 8; u++)
                ev[u] = embed[(size_t)(d0 + u) * NEMB + c];
#pragma unroll
            for (int u = 0; u < 8; u++)
#pragma unroll
                for (int j = 0; j < 8; j++)
                    s[j] = fmaf(xs[j][d0 + u], ev[u], s[j]);
        }
        const float e2 = enorm2[c];
#pragma unroll
        for (int j = 0; j < 8; j++) {
            float dist = fmaf(-2.f, s[j], e2);
            if (dist < best[j]) { best[j] = dist; bidx[j] = c; }
        }
    }
#pragma unroll
    for (int j = 0; j < 8; j++) { rv[j][t] = best[j]; ri[j][t] = bidx[j]; }
    __syncthreads();
    for (int off = 128; off > 0; off >>= 1) {
        if (t < off) {
#pragma unroll
            for (int j = 0; j < 8; j++) {
                float v = rv[j][t + off]; int i2 = ri[j][t + off];
                if (v < rv[j][t] || (v == rv[j][t] && i2 < ri[j][t])) {
                    rv[j][t] = v; ri[j][t] = i2;
                }
            }
        }
        __syncthreads();
    }
    if (t < nr) {
        int row = flaglist[base + t];
        int bi0 = ri[t][0];
        ind[row] = bi0;
        out_ind[row] = (float)bi0;
        atomicAdd(&counts[bi0], 1);
    }
}

// ---------- K2: quantize_st output + per-block diff partials ----------
__global__ __launch_bounds__(256) void k_quant(const float* __restrict__ input,
                                               const float* __restrict__ embedT,
                                               const int* __restrict__ ind,
                                               float* __restrict__ out_q,
                                               float* __restrict__ partials) {
    const int tid = threadIdx.x;
    const unsigned gid = blockIdx.x * 256 + tid;
    float s = 0.f;
#pragma unroll
    for (int j = 0; j < 8; j++) {
        size_t i4 = (size_t)gid + (size_t)j * 524288u;   // 4194304 float4 total
        int row = (int)(i4 >> 6);
        int d4  = (int)(i4 & 63);
        float4 iv = *reinterpret_cast<const float4*>(input + i4 * 4);
        int k = ind[row];
        float4 qv = *reinterpret_cast<const float4*>(embedT + (size_t)k * DIM + d4 * 4);
        float dx = qv.x - iv.x, dy = qv.y - iv.y, dz = qv.z - iv.z, dw = qv.w - iv.w;
        float4 ov;
        ov.x = iv.x + dx; ov.y = iv.y + dy; ov.z = iv.z + dz; ov.w = iv.w + dw;
        *reinterpret_cast<float4*>(out_q + i4 * 4) = ov;
        s += dx * dx + dy * dy + dz * dz + dw * dw;
    }
    __shared__ float red[256];
    red[tid] = s;
    __syncthreads();
    for (int off = 128; off > 0; off >>= 1) {
        if (tid < off) red[tid] += red[tid + off];
        __syncthreads();
    }
    if (tid == 0) partials[blockIdx.x] = red[0];
}

// ---------- K4: diff finalize + scans + ncs, n, cs ----------
__global__ __launch_bounds__(1024) void k_scan(const int* __restrict__ counts,
                                               const float* __restrict__ cluster_size,
                                               const float* __restrict__ qpartials,
                                               int* __restrict__ offsets,
                                               int* __restrict__ cursor,
                                               int* __restrict__ substart,
                                               float* __restrict__ out_ncs,
                                               float* __restrict__ cs,
                                               float* __restrict__ out_diff) {
    __shared__ int sh[NEMB];
    __shared__ float shf[NEMB];
    int tid = threadIdx.x;
    shf[tid] = qpartials[tid] + qpartials[tid + 1024];
    __syncthreads();
    for (int off = 512; off > 0; off >>= 1) {
        if (tid < off) shf[tid] += shf[tid + off];
        __syncthreads();
    }
    if (tid == 0) out_diff[0] = shf[0] / 16777216.0f;
    __syncthreads();
    int c = counts[tid];
    sh[tid] = c;
    __syncthreads();
    for (int off = 1; off < NEMB; off <<= 1) {
        int t = (tid >= off) ? sh[tid - off] : 0;
        __syncthreads();
        sh[tid] += t;
        __syncthreads();
    }
    int excl = sh[tid] - c;
    offsets[tid] = excl;
    cursor[tid]  = excl;
    int sc = (c + CH - 1) / CH;
    __syncthreads();
    sh[tid] = sc;
    __syncthreads();
    for (int off = 1; off < NEMB; off <<= 1) {
        int t = (tid >= off) ? sh[tid - off] : 0;
        __syncthreads();
        sh[tid] += t;
        __syncthreads();
    }
    substart[tid] = sh[tid] - sc;
    if (tid == NEMB - 1) substart[NEMB] = sh[tid];
    float ncs = cluster_size[tid] * DECAY + (1.f - DECAY) * (float)c;
    out_ncs[tid] = ncs;
    shf[tid] = ncs;
    __syncthreads();
    for (int off = 512; off > 0; off >>= 1) {
        if (tid < off) shf[tid] += shf[tid + off];
        __syncthreads();
    }
    float n = shf[0];
    cs[tid] = (ncs + EPS) / (n + NEMB * EPS) * n;
}

// ---------- K5: scatter rows by cluster ----------
__global__ __launch_bounds__(256) void k_scatter(const int* __restrict__ ind,
                                                 int* __restrict__ cursor,
                                                 int* __restrict__ sorted) {
    int i = blockIdx.x * 256 + threadIdx.x;
    int k = ind[i];
    int pos = atomicAdd(&cursor[k], 1);
    sorted[pos] = i;
}

// ---------- K6a: balanced partial sums. block = one 64-row sub-chunk ----------
__global__ __launch_bounds__(256) void k_psum(const float* __restrict__ input,
                                              const int* __restrict__ sorted,
                                              const int* __restrict__ counts,
                                              const int* __restrict__ offsets,
                                              const int* __restrict__ substart,
                                              float* __restrict__ partial) {
    const int b = blockIdx.x;
    if (b >= substart[NEMB]) return;
    int lo = 0, hi = NEMB;
    while (hi - lo > 1) {
        int mid = (lo + hi) >> 1;
        if (substart[mid] <= b) lo = mid; else hi = mid;
    }
    const int k     = lo;
    const int chunk = b - substart[k];
    const int cnt   = counts[k];
    const int base  = offsets[k] + chunk * CH;
    const int lim   = min(CH, cnt - chunk * CH);
    const int d     = threadIdx.x;
    float s = 0.f;
    for (int i = 0; i < lim; i++) {
        int row = sorted[base + i];
        s += input[(size_t)row * DIM + d];
    }
    partial[(size_t)b * DIM + d] = s;
}

// ---------- K6b: per-cluster combine (fixed order) + EMA + new_embed ----------
__global__ __launch_bounds__(256) void k_ema(const float* __restrict__ partial,
                                             const float* __restrict__ embed_avg,
                                             const int* __restrict__ substart,
                                             const float* __restrict__ cs,
                                             float* __restrict__ out_navg,
                                             float* __restrict__ out_nembed) {
    const int d = blockIdx.x;
    const int t = threadIdx.x;
#pragma unroll
    for (int i = 0; i < 4; i++) {
        int k = t + 256 * i;
        int s0 = substart[k], s1 = substart[k + 1];
        float s = 0.f;
        for (int sub = s0; sub < s1; sub++)
            s += partial[(size_t)sub * DIM + d];
        float navg = embed_avg[(size_t)d * NEMB + k] * (DECAY * DECAY) + (1.f - DECAY) * s;
        out_navg[(size_t)d * NEMB + k] = navg;
        out_nembed[(size_t)d * NEMB + k] = navg / cs[k];
    }
}

extern "C" void kernel_launch(void* const* d_in, const int* in_sizes, int n_in,
                              void* d_out, int out_size, void* d_ws, size_t ws_size,
                              hipStream_t stream) {
    const float* input        = (const float*)d_in[0];
    const float* embed        = (const float*)d_in[1];
    const float* cluster_size = (const float*)d_in[2];
    const float* embed_avg    = (const float*)d_in[3];

    float* out        = (float*)d_out;
    float* out_q      = out;                       // 16777216
    float* out_diff   = out + 16777216;            // 1
    float* out_ind    = out + 16777217;            // 65536
    float* out_ncs    = out + 16842753;            // 1024
    float* out_navg   = out + 16843777;            // 262144
    float* out_nembed = out + 17105921;            // 262144

    // candidate table (16 MB) lives in the out_q region; k_quant overwrites it later
    float4* tbl = (float4*)out_q;

    char* ws = (char*)d_ws;
    size_t o = 0;
    int*   w_ind      = (int*)(ws + o);   o += (size_t)NROWS * 4;
    float* w_embedT   = (float*)(ws + o); o += (size_t)DIM * NEMB * 4;
    float* w_enorm    = (float*)(ws + o); o += NEMB * 4;
    int*   w_counts   = (int*)(ws + o);   o += NEMB * 4;
    int*   w_offsets  = (int*)(ws + o);   o += NEMB * 4;
    int*   w_cursor   = (int*)(ws + o);   o += NEMB * 4;
    float* w_cs       = (float*)(ws + o); o += NEMB * 4;
    float* w_partials = (float*)(ws + o); o += 2048 * 4;
    int*   w_sorted   = (int*)(ws + o);   o += (size_t)NROWS * 4;
    int*   w_substart = (int*)(ws + o);   o += (NEMB + 4) * 4;
    float* w_partial  = (float*)(ws + o); o += (size_t)MAXSUB * DIM * 4;
    f16*   w_ehT      = (f16*)(ws + o);   o += (size_t)NEMB * 256 * 2;
    unsigned char* w_flags = (unsigned char*)(ws + o); o += NROWS;
    int*   w_flaglist = (int*)(ws + o);   o += (size_t)NROWS * 4;
    int*   w_nflag    = (int*)(ws + o);   o += 16;

    k_enorm<<<16, 256, 0, stream>>>(embed, w_enorm, w_counts, w_nflag);
    k_prep<<<dim3(32, 8), dim3(32, 8), 0, stream>>>(embed, w_embedT, w_ehT);
    k_argmin_mfma<<<4096, 256, 0, stream>>>(input, w_ehT, w_enorm, tbl);
    k_resolve<<<NROWS / 4, 256, 0, stream>>>(input, w_embedT, w_enorm, tbl,
                                             w_ind, out_ind, w_counts, w_flags);
    k_compact<<<NROWS / 256, 256, 0, stream>>>(w_flags, w_nflag, w_flaglist);
    k_fix<<<NROWS / 8, 256, 0, stream>>>(input, embed, w_enorm, w_flaglist, w_nflag,
                                         w_ind, out_ind, w_counts);
    k_quant<<<2048, 256, 0, stream>>>(input, w_embedT, w_ind, out_q, w_partials);
    k_scan<<<1, 1024, 0, stream>>>(w_counts, cluster_size, w_partials, w_offsets,
                                   w_cursor, w_substart, out_ncs, w_cs, out_diff);
    k_scatter<<<NROWS / 256, 256, 0, stream>>>(w_ind, w_cursor, w_sorted);
    k_psum<<<MAXSUB, 256, 0, stream>>>(input, w_sorted, w_counts, w_offsets,
                                       w_substart, w_partial);
    k_ema<<<DIM, 256, 0, stream>>>(w_partial, embed_avg, w_substart, w_cs,
                                   out_navg, out_nembed);
}

// Round 14
// 350.334 us; speedup vs baseline: 1.6347x; 1.6347x over previous
//
#include <hip/hip_runtime.h>
#include <float.h>

#define DECAY 0.99f
#define EPS 1e-5f
#define NROWS 65536
#define DIM 256
#define NEMB 1024
#define CH 64            // rows per sub-chunk in segmented reduction
#define MAXSUB 2048      // NROWS/CH + NEMB upper bound on total sub-chunks

#define GLOBAL_AS __attribute__((address_space(1)))
#define LOCAL_AS  __attribute__((address_space(3)))

typedef _Float16 f16;
typedef _Float16 half8 __attribute__((ext_vector_type(8)));
typedef float f32x4 __attribute__((ext_vector_type(4)));

// ---------- K0a: ||e_k||^2 per code + zero counts ----------
__global__ __launch_bounds__(256) void k_enorm(const float* __restrict__ embed,
                                               float* __restrict__ enorm2,
                                               int* __restrict__ counts) {
    int kk = threadIdx.x & 63;
    int dg = threadIdx.x >> 6;              // 0..3
    int k  = blockIdx.x * 64 + kk;          // 16 blocks * 64 = 1024 codes
    float s = 0.f;
    for (int d = dg; d < DIM; d += 4) {
        float v = embed[(size_t)d * NEMB + k];
        s = fmaf(v, v, s);
    }
    __shared__ float red[4][64];
    red[dg][kk] = s;
    __syncthreads();
    if (dg == 0) enorm2[k] = red[0][kk] + red[1][kk] + red[2][kk] + red[3][kk];
    int gt = blockIdx.x * 256 + threadIdx.x;
    if (gt < NEMB) counts[gt] = 0;
}

// ---------- K0b: fused transpose (embedT fp32) + hi/lo split (ehlT f16 [1024][512]) ----------
__global__ __launch_bounds__(256) void k_prep(const float* __restrict__ embed,
                                              float* __restrict__ embedT,
                                              f16* __restrict__ ehlT) {
    __shared__ float tile[32][33];           // [d-local][c-local]
    int c0 = blockIdx.x * 32, d0 = blockIdx.y * 32;
    int tx = threadIdx.x, ty = threadIdx.y;  // 32 x 8
#pragma unroll
    for (int i = 0; i < 4; i++)
        tile[ty + 8 * i][tx] = embed[(size_t)(d0 + ty + 8 * i) * NEMB + c0 + tx];
    __syncthreads();
#pragma unroll
    for (int i = 0; i < 4; i++) {
        int c = c0 + ty + 8 * i;
        int d = d0 + tx;
        float v = tile[tx][ty + 8 * i];
        embedT[(size_t)c * DIM + d] = v;
        f16 h = (f16)v;
        ehlT[(size_t)c * 512 + d]       = h;
        ehlT[(size_t)c * 512 + 256 + d] = (f16)(v - (float)h);
    }
}

// ---------- K1: mega-tile MFMA GEMM-argmin, exact 3-term, 4 iterations, ~10 barriers ----------
// Block = 256 rows x 256 cols; 512 threads = 8 waves (2M x 4N), wave tile 128x64.
// Grid = 1024: rowblock = bx>>2 (256 rows), colblock = bx&3 (256 cols). 1 block/CU.
// Per d-chunk dc (64 d's): stage Ah/Al ([256][64] f16, 32KB each; fp32->hi/lo in-reg,
// swizzled ds_write) + Beh/Bel (gload_lds, source-permuted). 2 barriers/iter.
// Compute: 3 terms (Ah*Beh + Al*Beh + Ah*Bel) x 2 k-steps x 32 MFMA = 192 MFMA/wave/iter.
// LDS tile addressing (both A and B): byte = idx*128 + ((slot*16) ^ ((idx&7)<<4)).
#define LDS_AH 0
#define LDS_AL 32768
#define LDS_BH 65536
#define LDS_BL 98304
#define LDS_SZ 131072

__global__ __launch_bounds__(512, 2) void k_argmin_mfma(const float* __restrict__ input,
                                                        const f16* __restrict__ ehlT,
                                                        const float* __restrict__ enorm2,
                                                        float2* __restrict__ tbl) {
    __shared__ char lds[LDS_SZ];
    const int tid  = threadIdx.x;
    const int lane = tid & 63;
    const int w    = tid >> 6;        // wave 0..7
    const int wm   = w >> 2;          // 0/1: rows wm*128..+128
    const int wn   = w & 3;           // 0..3: cols wn*64..+64
    const int bx   = blockIdx.x;
    const int rb   = (bx >> 2) * 256;
    const int cbi  = bx & 3;
    const int cb   = cbi * 256;
    const int l15  = lane & 15;
    const int lkh  = lane >> 4;       // 0..3
    // B staging source permutation (R6-proven): dest 16B chunk u -> tile row u>>3,
    // physical slot tid&7, logical slot = (tid&7)^((tid>>3)&7).
    const int slog = (tid & 7) ^ ((tid >> 3) & 7);

    // e2 for this wave's 64 cols
    float e2a[4];
#pragma unroll
    for (int fc = 0; fc < 4; ++fc) e2a[fc] = enorm2[cb + wn * 64 + fc * 16 + l15];

    f32x4 acc[8][4];
#pragma unroll
    for (int f = 0; f < 8; ++f)
#pragma unroll
        for (int fc = 0; fc < 4; ++fc) acc[f][fc] = (f32x4){0.f, 0.f, 0.f, 0.f};

#pragma unroll 1
    for (int dc = 0; dc < 4; ++dc) {
        if (dc) __syncthreads();    // close previous iteration's reads
        // ---- stage B: Beh + Bel (32KB each) via global_load_lds ----
#pragma unroll
        for (int j = 0; j < 4; ++j) {
            int u = tid + j * 512;           // 16B chunk id, 0..2047
            int col = u >> 3;                // tile col 0..255
            const f16* seh = ehlT + (size_t)(cb + col) * 512 + dc * 64 + slog * 8;
            __builtin_amdgcn_global_load_lds((const GLOBAL_AS unsigned*)seh,
                (LOCAL_AS unsigned*)(lds + LDS_BH + u * 16), 16, 0, 0);
            __builtin_amdgcn_global_load_lds((const GLOBAL_AS unsigned*)(seh + 256),
                (LOCAL_AS unsigned*)(lds + LDS_BL + u * 16), 16, 0, 0);
        }
        // ---- stage A: 256 rows x 64 d fp32 -> hi/lo f16, swizzled ds_write ----
        {
            const int row  = tid >> 1;       // 0..255
            const int half = tid & 1;        // d-sub: k 0..31 / 32..63
            const float* gp = input + (size_t)(rb + row) * DIM + dc * 64 + half * 32;
            const int sw = (row & 7) << 4;
            const int rbase = row * 128;
#pragma unroll
            for (int u = 0; u < 4; ++u) {    // 8 floats per batch (bounded registers)
                float4 a = *(const float4*)(gp + u * 8);
                float4 b = *(const float4*)(gp + u * 8 + 4);
                float fv[8] = {a.x, a.y, a.z, a.w, b.x, b.y, b.z, b.w};
                half8 hh, ll;
#pragma unroll
                for (int e = 0; e < 8; ++e) {
                    f16 h = (f16)fv[e];
                    hh[e] = h;
                    ll[e] = (f16)(fv[e] - (float)h);
                }
                const int slot = half * 4 + u;
                *(half8*)(lds + LDS_AH + rbase + ((slot * 16) ^ sw)) = hh;
                *(half8*)(lds + LDS_AL + rbase + ((slot * 16) ^ sw)) = ll;
            }
        }
        __syncthreads();   // drains gload_lds (vmcnt) + ds_writes (lgkm)

        // ---- compute: 3 exact terms, 2 k-steps each ----
#pragma unroll
        for (int term = 0; term < 3; ++term) {
            const char* Ab = lds + (term == 1 ? LDS_AL : LDS_AH);
            const char* Bb = lds + (term == 2 ? LDS_BL : LDS_BH);
#pragma unroll
            for (int kk = 0; kk < 2; ++kk) {
                const int slot = kk * 4 + lkh;
                half8 af[8], bf[4];
#pragma unroll
                for (int f = 0; f < 8; ++f) {
                    int row = wm * 128 + f * 16 + l15;
                    af[f] = *(const half8*)(Ab + row * 128 + ((slot * 16) ^ ((row & 7) << 4)));
                }
#pragma unroll
                for (int fc = 0; fc < 4; ++fc) {
                    int col = wn * 64 + fc * 16 + l15;
                    bf[fc] = *(const half8*)(Bb + col * 128 + ((slot * 16) ^ ((col & 7) << 4)));
                }
                __builtin_amdgcn_s_setprio(1);
#pragma unroll
                for (int f = 0; f < 8; ++f)
#pragma unroll
                    for (int fc = 0; fc < 4; ++fc)
                        acc[f][fc] = __builtin_amdgcn_mfma_f32_16x16x32_f16(
                            af[f], bf[fc], acc[f][fc], 0, 0, 0);
                __builtin_amdgcn_s_setprio(0);
            }
        }
    }
    __syncthreads();   // all compute done; safe to overlay PW/PI on LDS_BH

    // ---- epilogue: per-row min over this wave's 64 cols ----
    float* PW = (float*)(lds + LDS_BH);          // [256][4]
    int*   PI = (int*)(lds + LDS_BH + 4096);     // [256][4]
#pragma unroll
    for (int f = 0; f < 8; ++f)
#pragma unroll
        for (int r = 0; r < 4; ++r) {
            float best = fmaf(-2.f, acc[f][0][r], e2a[0]);
            int   bi_  = cb + wn * 64 + l15;
#pragma unroll
            for (int fc = 1; fc < 4; ++fc) {
                float s = fmaf(-2.f, acc[f][fc][r], e2a[fc]);
                int col = cb + wn * 64 + fc * 16 + l15;
                if (s < best) { best = s; bi_ = col; }   // fc ascending: lowest col on tie
            }
#pragma unroll
            for (int m = 1; m <= 8; m <<= 1) {
                float ov = __shfl_xor(best, m, 64);
                int   oi = __shfl_xor(bi_, m, 64);
                if (ov < best || (ov == best && oi < bi_)) { best = ov; bi_ = oi; }
            }
            if (l15 == 0) {
                int row = wm * 128 + f * 16 + lkh * 4 + r;
                PW[row * 4 + wn] = best;
                PI[row * 4 + wn] = bi_;
            }
        }
    __syncthreads();
    if (tid < 256) {
        float v = PW[tid * 4]; int i = PI[tid * 4];
#pragma unroll
        for (int t = 1; t < 4; ++t) {
            float ov = PW[tid * 4 + t]; int oi = PI[tid * 4 + t];
            if (ov < v || (ov == v && oi < i)) { v = ov; i = oi; }
        }
        float2 o; o.x = v; o.y = __int_as_float(i);
        tbl[(size_t)(rb + tid) * 4 + cbi] = o;
    }
}

// ---------- K1b: merge 4 colblocks per row; write ind + fused histogram ----------
__global__ __launch_bounds__(256) void k_merge(const float2* __restrict__ tbl,
                                               int* __restrict__ ind,
                                               float* __restrict__ out_ind,
                                               int* __restrict__ counts) {
    int r = blockIdx.x * 256 + threadIdx.x;
    float2 t0 = tbl[(size_t)r * 4];
    float v = t0.x; int i = __float_as_int(t0.y);
#pragma unroll
    for (int c = 1; c < 4; ++c) {
        float2 t = tbl[(size_t)r * 4 + c];
        int oi = __float_as_int(t.y);
        if (t.x < v || (t.x == v && oi < i)) { v = t.x; i = oi; }
    }
    ind[r] = i;
    out_ind[r] = (float)i;
    atomicAdd(&counts[i], 1);
}

// ---------- K2: quantize_st output + per-block diff partials ----------
__global__ __launch_bounds__(256) void k_quant(const float* __restrict__ input,
                                               const float* __restrict__ embedT,
                                               const int* __restrict__ ind,
                                               float* __restrict__ out_q,
                                               float* __restrict__ partials) {
    const int tid = threadIdx.x;
    const unsigned gid = blockIdx.x * 256 + tid;
    float s = 0.f;
#pragma unroll
    for (int j = 0; j < 8; j++) {
        size_t i4 = (size_t)gid + (size_t)j * 524288u;   // 4194304 float4 total
        int row = (int)(i4 >> 6);
        int d4  = (int)(i4 & 63);
        float4 iv = *reinterpret_cast<const float4*>(input + i4 * 4);
        int k = ind[row];
        float4 qv = *reinterpret_cast<const float4*>(embedT + (size_t)k * DIM + d4 * 4);
        float dx = qv.x - iv.x, dy = qv.y - iv.y, dz = qv.z - iv.z, dw = qv.w - iv.w;
        float4 ov;
        ov.x = iv.x + dx; ov.y = iv.y + dy; ov.z = iv.z + dz; ov.w = iv.w + dw;
        *reinterpret_cast<float4*>(out_q + i4 * 4) = ov;
        s += dx * dx + dy * dy + dz * dz + dw * dw;
    }
    __shared__ float red[256];
    red[tid] = s;
    __syncthreads();
    for (int off = 128; off > 0; off >>= 1) {
        if (tid < off) red[tid] += red[tid + off];
        __syncthreads();
    }
    if (tid == 0) partials[blockIdx.x] = red[0];
}

// ---------- K4: diff finalize + scans + ncs, n, cs ----------
__global__ __launch_bounds__(1024) void k_scan(const int* __restrict__ counts,
                                               const float* __restrict__ cluster_size,
                                               const float* __restrict__ qpartials,
                                               int* __restrict__ offsets,
                                               int* __restrict__ cursor,
                                               int* __restrict__ substart,
                                               float* __restrict__ out_ncs,
                                               float* __restrict__ cs,
                                               float* __restrict__ out_diff) {
    __shared__ int sh[NEMB];
    __shared__ float shf[NEMB];
    int tid = threadIdx.x;
    shf[tid] = qpartials[tid] + qpartials[tid + 1024];
    __syncthreads();
    for (int off = 512; off > 0; off >>= 1) {
        if (tid < off) shf[tid] += shf[tid + off];
        __syncthreads();
    }
    if (tid == 0) out_diff[0] = shf[0] / 16777216.0f;
    __syncthreads();
    int c = counts[tid];
    sh[tid] = c;
    __syncthreads();
    for (int off = 1; off < NEMB; off <<= 1) {
        int t = (tid >= off) ? sh[tid - off] : 0;
        __syncthreads();
        sh[tid] += t;
        __syncthreads();
    }
    int excl = sh[tid] - c;
    offsets[tid] = excl;
    cursor[tid]  = excl;
    int sc = (c + CH - 1) / CH;
    __syncthreads();
    sh[tid] = sc;
    __syncthreads();
    for (int off = 1; off < NEMB; off <<= 1) {
        int t = (tid >= off) ? sh[tid - off] : 0;
        __syncthreads();
        sh[tid] += t;
        __syncthreads();
    }
    substart[tid] = sh[tid] - sc;
    if (tid == NEMB - 1) substart[NEMB] = sh[tid];
    float ncs = cluster_size[tid] * DECAY + (1.f - DECAY) * (float)c;
    out_ncs[tid] = ncs;
    shf[tid] = ncs;
    __syncthreads();
    for (int off = 512; off > 0; off >>= 1) {
        if (tid < off) shf[tid] += shf[tid + off];
        __syncthreads();
    }
    float n = shf[0];
    cs[tid] = (ncs + EPS) / (n + NEMB * EPS) * n;
}

// ---------- K5: scatter rows by cluster ----------
__global__ __launch_bounds__(256) void k_scatter(const int* __restrict__ ind,
                                                 int* __restrict__ cursor,
                                                 int* __restrict__ sorted) {
    int i = blockIdx.x * 256 + threadIdx.x;
    int k = ind[i];
    int pos = atomicAdd(&cursor[k], 1);
    sorted[pos] = i;
}

// ---------- K6a: balanced partial sums. block = one 64-row sub-chunk ----------
__global__ __launch_bounds__(256) void k_psum(const float* __restrict__ input,
                                              const int* __restrict__ sorted,
                                              const int* __restrict__ counts,
                                              const int* __restrict__ offsets,
                                              const int* __restrict__ substart,
                                              float* __restrict__ partial) {
    const int b = blockIdx.x;
    if (b >= substart[NEMB]) return;
    int lo = 0, hi = NEMB;
    while (hi - lo > 1) {
        int mid = (lo + hi) >> 1;
        if (substart[mid] <= b) lo = mid; else hi = mid;
    }
    const int k     = lo;
    const int chunk = b - substart[k];
    const int cnt   = counts[k];
    const int base  = offsets[k] + chunk * CH;
    const int lim   = min(CH, cnt - chunk * CH);
    const int d     = threadIdx.x;
    float s = 0.f;
    for (int i = 0; i < lim; i++) {
        int row = sorted[base + i];
        s += input[(size_t)row * DIM + d];
    }
    partial[(size_t)b * DIM + d] = s;
}

// ---------- K6b: per-cluster combine (fixed order) + EMA + new_embed ----------
__global__ __launch_bounds__(256) void k_ema(const float* __restrict__ partial,
                                             const float* __restrict__ embed_avg,
                                             const int* __restrict__ substart,
                                             const float* __restrict__ cs,
                                             float* __restrict__ out_navg,
                                             float* __restrict__ out_nembed) {
    const int d = blockIdx.x;
    const int t = threadIdx.x;
#pragma unroll
    for (int i = 0; i < 4; i++) {
        int k = t + 256 * i;
        int s0 = substart[k], s1 = substart[k + 1];
        float s = 0.f;
        for (int sub = s0; sub < s1; sub++)
            s += partial[(size_t)sub * DIM + d];
        float navg = embed_avg[(size_t)d * NEMB + k] * (DECAY * DECAY) + (1.f - DECAY) * s;
        out_navg[(size_t)d * NEMB + k] = navg;
        out_nembed[(size_t)d * NEMB + k] = navg / cs[k];
    }
}

extern "C" void kernel_launch(void* const* d_in, const int* in_sizes, int n_in,
                              void* d_out, int out_size, void* d_ws, size_t ws_size,
                              hipStream_t stream) {
    const float* input        = (const float*)d_in[0];
    const float* embed        = (const float*)d_in[1];
    const float* cluster_size = (const float*)d_in[2];
    const float* embed_avg    = (const float*)d_in[3];

    float* out        = (float*)d_out;
    float* out_q      = out;                       // 16777216
    float* out_diff   = out + 16777216;            // 1
    float* out_ind    = out + 16777217;            // 65536
    float* out_ncs    = out + 16842753;            // 1024
    float* out_navg   = out + 16843777;            // 262144
    float* out_nembed = out + 17105921;            // 262144

    char* ws = (char*)d_ws;
    size_t o = 0;
    int*   w_ind      = (int*)(ws + o);   o += (size_t)NROWS * 4;
    float* w_embedT   = (float*)(ws + o); o += (size_t)DIM * NEMB * 4;
    float* w_enorm    = (float*)(ws + o); o += NEMB * 4;
    int*   w_counts   = (int*)(ws + o);   o += NEMB * 4;
    int*   w_offsets  = (int*)(ws + o);   o += NEMB * 4;
    int*   w_cursor   = (int*)(ws + o);   o += NEMB * 4;
    float* w_cs       = (float*)(ws + o); o += NEMB * 4;
    float* w_partials = (float*)(ws + o); o += 2048 * 4;
    int*   w_sorted   = (int*)(ws + o);   o += (size_t)NROWS * 4;
    int*   w_substart = (int*)(ws + o);   o += (NEMB + 4) * 4;
    float* w_partial  = (float*)(ws + o); o += (size_t)MAXSUB * DIM * 4;
    f16*   w_ehlT     = (f16*)(ws + o);   o += (size_t)NEMB * 512 * 2;
    float2* w_tbl     = (float2*)(ws + o); o += (size_t)NROWS * 4 * 8;

    k_enorm<<<16, 256, 0, stream>>>(embed, w_enorm, w_counts);
    k_prep<<<dim3(32, 8), dim3(32, 8), 0, stream>>>(embed, w_embedT, w_ehlT);
    k_argmin_mfma<<<1024, 512, 0, stream>>>(input, w_ehlT, w_enorm, w_tbl);
    k_merge<<<NROWS / 256, 256, 0, stream>>>(w_tbl, w_ind, out_ind, w_counts);
    k_quant<<<2048, 256, 0, stream>>>(input, w_embedT, w_ind, out_q, w_partials);
    k_scan<<<1, 1024, 0, stream>>>(w_counts, cluster_size, w_partials, w_offsets,
                                   w_cursor, w_substart, out_ncs, w_cs, out_diff);
    k_scatter<<<NROWS / 256, 256, 0, stream>>>(w_ind, w_cursor, w_sorted);
    k_psum<<<MAXSUB, 256, 0, stream>>>(input, w_sorted, w_counts, w_offsets,
                                       w_substart, w_partial);
    k_ema<<<DIM, 256, 0, stream>>>(w_partial, embed_avg, w_substart, w_cs,
                                   out_navg, out_nembed);
}